// Round 1
// baseline (2241.057 us; speedup 1.0000x reference)
//
#include <hip/hip_runtime.h>
#include <stdint.h>

typedef unsigned short u16;
typedef __attribute__((ext_vector_type(8))) short s8v;
typedef __attribute__((ext_vector_type(4))) float f4v;

#define D_     1024
#define HEADS_ 16
#define DH_    64
#define B_     2
#define T_     16
#define H_     9
#define W_     16
#define HW_    144
#define NTOK_  4608
#define MLPH_  4096
#define STRIDE_ 5
#define PI_    3.14159265358979323846f

__device__ __forceinline__ float b2f(u16 u){
  union{float f; unsigned int i;} c; c.i = ((unsigned int)u)<<16; return c.f;
}
__device__ __forceinline__ u16 f2b(float f){
  union{float f; unsigned int i;} c; c.f = f;
  unsigned int r = c.i + 0x7FFFu + ((c.i >> 16) & 1u);
  return (u16)(r >> 16);
}
__device__ __forceinline__ float elu1f(float x){ return x > 0.f ? x + 1.f : expf(x); }

// ---------------- weight transpose + f32->bf16: in (K,N) -> out (N,K) ----------------
__global__ __launch_bounds__(256) void transpose_w(const float* __restrict__ in,
                                                   u16* __restrict__ out, int K, int N)
{
  __shared__ float tile[32][33];
  int n0 = blockIdx.x*32, k0 = blockIdx.y*32;
  int tx = threadIdx.x & 31, ty = threadIdx.x >> 5;   // 32 x 8
  #pragma unroll
  for (int i=0;i<4;i++)
    tile[ty+i*8][tx] = in[(size_t)(k0+ty+i*8)*N + n0+tx];
  __syncthreads();
  #pragma unroll
  for (int i=0;i<4;i++)
    out[(size_t)(n0+ty+i*8)*K + k0+tx] = f2b(tile[tx][ty+i*8]);
}

// ---------------- silu ----------------
__global__ void silu_k(const float* __restrict__ c, float* __restrict__ out, int n){
  int i = blockIdx.x*256 + threadIdx.x;
  if (i < n){ float v = c[i]; out[i] = v / (1.f + __expf(-v)); }
}

// ---------------- ada GEMM: out[32][6144] = sc[32][1024] @ w[1024][6144] + b ----------------
__global__ __launch_bounds__(256) void ada_gemm(const float* __restrict__ sc,
                                                const float* __restrict__ w,
                                                const float* __restrict__ b,
                                                float* __restrict__ out)
{
  int j = blockIdx.x*256 + threadIdx.x;
  __shared__ float scl[32*64];
  float acc[32];
  #pragma unroll
  for (int r=0;r<32;r++) acc[r]=0.f;
  for (int k0=0;k0<1024;k0+=64) {
    __syncthreads();
    for (int idx=threadIdx.x; idx<2048; idx+=256) {
      int r = idx>>6, kk = idx&63;
      scl[r*64+kk] = sc[r*1024 + k0 + kk];
    }
    __syncthreads();
    for (int kk=0;kk<64;kk++) {
      float wv = w[(size_t)(k0+kk)*6144 + j];
      #pragma unroll
      for (int r=0;r<32;r++) acc[r] += scl[r*64+kk]*wv;
    }
  }
  float bb = b[j];
  #pragma unroll
  for (int r=0;r<32;r++) out[(size_t)r*6144 + j] = acc[r] + bb;
}

// ---------------- LayerNorm + modulation -> bf16 ----------------
__global__ __launch_bounds__(256) void ln_mod(const float* __restrict__ x,
                                              const float* __restrict__ ada,
                                              int shOff, int scOff,
                                              u16* __restrict__ out)
{
  int n = blockIdx.x, tid = threadIdx.x;
  const float* xr = x + (size_t)n * D_;
  float4 v = *(const float4*)&xr[tid*4];
  float s = v.x+v.y+v.z+v.w;
  __shared__ float red[8];
  for (int o=32;o;o>>=1) s += __shfl_down(s,o,64);
  if ((tid&63)==0) red[tid>>6] = s;
  __syncthreads();
  float mean = (red[0]+red[1]+red[2]+red[3]) * (1.f/D_);
  float d0=v.x-mean, d1=v.y-mean, d2=v.z-mean, d3=v.w-mean;
  float sq = d0*d0+d1*d1+d2*d2+d3*d3;
  for (int o=32;o;o>>=1) sq += __shfl_down(sq,o,64);
  if ((tid&63)==0) red[4+(tid>>6)] = sq;
  __syncthreads();
  float var = (red[4]+red[5]+red[6]+red[7]) * (1.f/D_);
  float rstd = rsqrtf(var + 1e-6f);
  int bt = n / HW_;
  const float* adar = ada + (size_t)bt*6*D_;
  int cidx = tid*4;
  float4 sh = *(const float4*)&adar[shOff + cidx];
  float4 sc = *(const float4*)&adar[scOff + cidx];
  ushort4 o4;
  o4.x = f2b(d0*rstd*(1.f+sc.x)+sh.x);
  o4.y = f2b(d1*rstd*(1.f+sc.y)+sh.y);
  o4.z = f2b(d2*rstd*(1.f+sc.z)+sh.z);
  o4.w = f2b(d3*rstd*(1.f+sc.w)+sh.w);
  *(ushort4*)&out[(size_t)n*D_ + cidx] = o4;
}

// ---------------- MFMA GEMM: C(MxN) = A(MxK bf16) x Bt(NxK bf16)^T ----------------
// MODE 0: store f32
// MODE 1: +bias, gelu(tanh), store bf16
// MODE 2: +bias, *(1+ada[bt][adaOff+c]), store f32
// MODE 3: +bias, *ada[bt][adaOff+c], += xprev, store f32
template<int MODE>
__global__ __launch_bounds__(256) void gemm_bt(
    const u16* __restrict__ A, const u16* __restrict__ Bt,
    float* __restrict__ Cf, u16* __restrict__ Cb,
    const float* __restrict__ bias, const float* __restrict__ ada, int adaOff,
    const float* __restrict__ xprev, int M, int N, int K)
{
  __shared__ u16 As[128*32];
  __shared__ u16 Bs[128*32];
  const int tid = threadIdx.x;
  const int row0 = blockIdx.y*128, col0 = blockIdx.x*128;
  const int lane = tid & 63, wid = tid >> 6;
  const int wr = wid >> 1, wc = wid & 1;
  const int r16 = lane & 15, kg = lane >> 4;

  f4v acc[4][4] = {};
  const int sr = tid >> 2;
  const int sc = (tid & 3) * 8;
  const u16* Ag = A + (size_t)(row0 + sr) * K + sc;
  const u16* Bg = Bt + (size_t)(col0 + sr) * K + sc;

  for (int k0 = 0; k0 < K; k0 += 32) {
    __syncthreads();
    uint4 a0 = *(const uint4*)(Ag + k0);
    uint4 a1 = *(const uint4*)(Ag + (size_t)64*K + k0);
    uint4 b0 = *(const uint4*)(Bg + k0);
    uint4 b1 = *(const uint4*)(Bg + (size_t)64*K + k0);
    *(uint4*)&As[sr*32 + sc]      = a0;
    *(uint4*)&As[(sr+64)*32 + sc] = a1;
    *(uint4*)&Bs[sr*32 + sc]      = b0;
    *(uint4*)&Bs[(sr+64)*32 + sc] = b1;
    __syncthreads();
    s8v af[4], bfv[4];
    #pragma unroll
    for (int mi=0; mi<4; mi++)
      af[mi] = *(const s8v*)&As[(wr*64 + mi*16 + r16)*32 + kg*8];
    #pragma unroll
    for (int ni=0; ni<4; ni++)
      bfv[ni] = *(const s8v*)&Bs[(wc*64 + ni*16 + r16)*32 + kg*8];
    #pragma unroll
    for (int mi=0; mi<4; mi++)
      #pragma unroll
      for (int ni=0; ni<4; ni++)
        acc[mi][ni] = __builtin_amdgcn_mfma_f32_16x16x32_bf16(af[mi], bfv[ni], acc[mi][ni], 0,0,0);
  }
  #pragma unroll
  for (int mi=0; mi<4; mi++)
  #pragma unroll
  for (int ni=0; ni<4; ni++) {
    int rbase = row0 + wr*64 + mi*16 + (lane>>4)*4;
    int c = col0 + wc*64 + ni*16 + (lane&15);
    #pragma unroll
    for (int q=0; q<4; q++) {
      int r = rbase + q;
      float v = acc[mi][ni][q];
      if (MODE == 0) {
        Cf[(size_t)r*N + c] = v;
      } else if (MODE == 1) {
        v += bias[c];
        float t = 0.7978845608028654f * (v + 0.044715f*v*v*v);
        Cb[(size_t)r*N + c] = f2b(0.5f*v*(1.f + tanhf(t)));
      } else if (MODE == 2) {
        v += bias[c];
        float g = ada[(size_t)(r/HW_)*(6*D_) + adaOff + c];
        Cf[(size_t)r*N + c] = v*(1.f+g);
      } else {
        v += bias[c];
        float g = ada[(size_t)(r/HW_)*(6*D_) + adaOff + c];
        Cf[(size_t)r*N + c] = xprev[(size_t)r*N + c] + v*g;
      }
    }
  }
}

// ---------------- spatial memory update (pre-RoPE k,v) ----------------
__global__ __launch_bounds__(256) void memupd_s_k(
  const float* __restrict__ qkv, const float* __restrict__ mem_in, const float* __restrict__ z_in,
  float* __restrict__ mem_out, float* __restrict__ z_out)
{
  int head = blockIdx.x, f = blockIdx.y;
  __shared__ float ek[STRIDE_][DH_];
  __shared__ float ev[STRIDE_][DH_];
  int tid = threadIdx.x;
  const size_t base = (size_t)f*HW_*(3*D_) + (size_t)head*DH_;
  for (int i = tid; i < STRIDE_*DH_; i += 256) {
    int s = i/DH_, d = i%DH_;
    float kv = qkv[base + (size_t)s*(3*D_) + D_ + d];
    ek[s][d] = elu1f(kv) + 1.f;   // elu1(elu1(k)) = elu1(k)+1 since elu1>0
    ev[s][d] = qkv[base + (size_t)s*(3*D_) + 2*D_ + d];
  }
  __syncthreads();
  size_t mbase = ((size_t)f*HEADS_ + head)*DH_*DH_;
  for (int i = tid; i < DH_*DH_; i += 256) {
    int d = i>>6, j = i&63;
    float s = 0.f;
    #pragma unroll
    for (int t=0;t<STRIDE_;t++) s += ek[t][d]*ev[t][j];
    mem_out[mbase+i] = mem_in[mbase+i] + s;
  }
  if (tid < DH_) {
    float s = 0.f;
    for (int t=0;t<HW_;t++)
      s += elu1f(qkv[base + (size_t)t*(3*D_) + D_ + tid]);
    size_t zb = ((size_t)f*HEADS_+head)*DH_ + tid;
    z_out[zb] = z_in[zb] + s;
  }
}

// ---------------- temporal memory update ----------------
__global__ __launch_bounds__(256) void memupd_t_k(
  const float* __restrict__ qkv, const float* __restrict__ mem_in, const float* __restrict__ z_in,
  float* __restrict__ mem_out, float* __restrict__ z_out)
{
  int head = blockIdx.x, g = blockIdx.y;
  int b = g / HW_, hw = g % HW_;
  size_t tok0 = (size_t)b*T_*HW_ + hw;
  __shared__ float ek[STRIDE_][DH_];
  __shared__ float ev[STRIDE_][DH_];
  int tid = threadIdx.x;
  for (int i = tid; i < STRIDE_*DH_; i += 256) {
    int t = i/DH_, d = i%DH_;
    size_t a = (tok0 + (size_t)t*HW_)*(3*D_) + (size_t)head*DH_;
    float kv = qkv[a + D_ + d];
    ek[t][d] = elu1f(kv) + 1.f;
    ev[t][d] = qkv[a + 2*D_ + d];
  }
  __syncthreads();
  size_t mbase = ((size_t)g*HEADS_ + head)*DH_*DH_;
  for (int i = tid; i < DH_*DH_; i += 256) {
    int d = i>>6, j = i&63;
    float s = 0.f;
    #pragma unroll
    for (int t=0;t<STRIDE_;t++) s += ek[t][d]*ev[t][j];
    mem_out[mbase+i] = mem_in[mbase+i] + s;
  }
  if (tid < DH_) {
    float s = 0.f;
    for (int t=0;t<T_;t++)
      s += elu1f(qkv[(tok0 + (size_t)t*HW_)*(3*D_) + D_ + (size_t)head*DH_ + tid]);
    size_t zb = ((size_t)g*HEADS_+head)*DH_ + tid;
    z_out[zb] = z_in[zb] + s;
  }
}

// ---------------- RoPE (in-place on q,k of qkv buffer) ----------------
__global__ __launch_bounds__(256) void rope_s_k(float* __restrict__ qkv)
{
  int n = blockIdx.x;
  int hw = n % HW_;
  int h = hw / W_, w = hw % W_;
  float* qb = qkv + (size_t)n*(3*D_);
  int tid = threadIdx.x;
  #pragma unroll
  for (int rep=0; rep<2; rep++) {
    int p = tid + rep*256;
    int col = p*2;
    int dh = col & 63;
    int i2 = dh >> 1;
    float fv;
    if (i2 < 16) {
      float pos = -1.f + (float)h*(2.f/8.f);
      fv = pos * ((1.f + (float)i2*(127.f/15.f)) * PI_);
    } else {
      float pos = -1.f + (float)w*(2.f/15.f);
      fv = pos * ((1.f + (float)(i2-16)*(127.f/15.f)) * PI_);
    }
    float cs = cosf(fv), sn = sinf(fv);
    float2 q2 = *(float2*)&qb[col];
    float2 k2 = *(float2*)&qb[D_+col];
    float2 qo, ko;
    qo.x = q2.x*cs - q2.y*sn;  qo.y = q2.y*cs + q2.x*sn;
    ko.x = k2.x*cs - k2.y*sn;  ko.y = k2.y*cs + k2.x*sn;
    *(float2*)&qb[col]    = qo;
    *(float2*)&qb[D_+col] = ko;
  }
}

__global__ __launch_bounds__(256) void rope_t_k(float* __restrict__ qkv)
{
  int n = blockIdx.x;
  int t = (n / HW_) % T_;
  float* qb = qkv + (size_t)n*(3*D_);
  int tid = threadIdx.x;
  #pragma unroll
  for (int rep=0; rep<2; rep++) {
    int p = tid + rep*256;
    int col = p*2;
    int dh = col & 63;
    int i2 = dh >> 1;
    float inv = expf(-(float)i2 * (9.210340371976184f/32.f));  // 10000^(-i2/32)
    float fv = (float)t * inv;
    float cs = cosf(fv), sn = sinf(fv);
    float2 q2 = *(float2*)&qb[col];
    float2 k2 = *(float2*)&qb[D_+col];
    float2 qo, ko;
    qo.x = q2.x*cs - q2.y*sn;  qo.y = q2.y*cs + q2.x*sn;
    ko.x = k2.x*cs - k2.y*sn;  ko.y = k2.y*cs + k2.x*sn;
    *(float2*)&qb[col]    = qo;
    *(float2*)&qb[D_+col] = ko;
  }
}

// ---------------- spatial attention: sdpa(144) + retrieve + combine -> bf16 o ----------------
__global__ __launch_bounds__(256) void attn_s_k(
  const float* __restrict__ qkv, const float* __restrict__ mem, const float* __restrict__ z,
  const float* __restrict__ beta, u16* __restrict__ o)
{
  int head = blockIdx.x, f = blockIdx.y;
  __shared__ u16 Kl[DH_][HW_];    // [d][j]
  __shared__ u16 Vl[HW_][DH_];    // [j][d]
  __shared__ float pl[4][HW_];
  int tid = threadIdx.x, lane = tid & 63, wv = tid >> 6;
  const size_t base = (size_t)f*HW_*(3*D_) + (size_t)head*DH_;
  for (int idx=tid; idx<HW_*DH_; idx+=256) {
    int j = idx>>6, d = idx&63;
    Kl[d][j] = f2b(qkv[base + (size_t)j*(3*D_) + D_ + d]);
    Vl[j][d] = f2b(qkv[base + (size_t)j*(3*D_) + 2*D_ + d]);
  }
  __syncthreads();
  float g = 1.f/(1.f+__expf(-beta[head]));
  const float* memh = mem + ((size_t)f*HEADS_+head)*DH_*DH_;
  const float* zh   = z   + ((size_t)f*HEADS_+head)*DH_;
  for (int i=wv; i<HW_; i+=4) {
    const float* qrow = qkv + base + (size_t)i*(3*D_);
    float s0=0.f, s1=0.f, s2=0.f;
    for (int d=0; d<DH_; d++) {
      float qd = qrow[d];
      s0 += qd * b2f(Kl[d][lane]);
      s1 += qd * b2f(Kl[d][lane+64]);
      if (lane < (HW_-128)) s2 += qd * b2f(Kl[d][lane+128]);
    }
    s0 *= 0.125f; s1 *= 0.125f; s2 *= 0.125f;
    float m = fmaxf(s0, s1);
    if (lane < (HW_-128)) m = fmaxf(m, s2);
    for (int o2=32;o2;o2>>=1) m = fmaxf(m, __shfl_xor(m,o2,64));
    float p0 = __expf(s0-m), p1 = __expf(s1-m);
    float p2 = (lane < (HW_-128)) ? __expf(s2-m) : 0.f;
    float sum = p0+p1+p2;
    for (int o2=32;o2;o2>>=1) sum += __shfl_xor(sum,o2,64);
    float inv = 1.f/sum;
    pl[wv][lane]    = p0*inv;
    pl[wv][lane+64] = p1*inv;
    if (lane < (HW_-128)) pl[wv][lane+128] = p2*inv;
    // same-wave LDS ordering: no barrier needed
    float oatt = 0.f;
    for (int j=0;j<HW_;j++) oatt += pl[wv][j] * b2f(Vl[j][lane]);
    float num=0.f, den=0.f;
    for (int dd=0; dd<DH_; dd++) {
      float sq = elu1f(qrow[dd]);
      num += sq * memh[dd*DH_ + lane];
      den += sq * zh[dd];
    }
    float ov = g*(num/den) + (1.f-g)*oatt;
    o[((size_t)f*HW_ + i)*D_ + (size_t)head*DH_ + lane] = f2b(ov);
  }
}

// ---------------- temporal attention: causal sdpa(16) + retrieve + combine ----------------
__global__ __launch_bounds__(64) void attn_t_k(
  const float* __restrict__ qkv, const float* __restrict__ mem, const float* __restrict__ z,
  const float* __restrict__ beta, u16* __restrict__ o)
{
  int head = blockIdx.x, gi = blockIdx.y;
  int b = gi / HW_, hw = gi % HW_;
  __shared__ float Kl[DH_][T_];   // [d][t]
  __shared__ float Vl[T_][DH_];
  __shared__ float pl[T_];
  int lane = threadIdx.x;
  size_t tok0 = (size_t)b*T_*HW_ + hw;
  for (int idx=lane; idx<T_*DH_; idx+=64) {
    int t = idx>>6, d = idx&63;
    size_t a = (tok0 + (size_t)t*HW_)*(3*D_) + (size_t)head*DH_;
    Kl[d][t] = qkv[a + D_ + d];
    Vl[t][d] = qkv[a + 2*D_ + d];
  }
  __syncthreads();
  float g = 1.f/(1.f+__expf(-beta[head]));
  const float* memh = mem + ((size_t)gi*HEADS_+head)*DH_*DH_;
  const float* zh   = z   + ((size_t)gi*HEADS_+head)*DH_;
  for (int i=0;i<T_;i++) {
    const float* qrow = qkv + (tok0 + (size_t)i*HW_)*(3*D_) + (size_t)head*DH_;
    float s = 0.f;
    if (lane <= i) {
      for (int d=0; d<DH_; d++) s += qrow[d]*Kl[d][lane];
      s *= 0.125f;
    }
    float sv = (lane<=i) ? s : -3.4e38f;
    float m = sv;
    for (int o2=32;o2;o2>>=1) m = fmaxf(m, __shfl_xor(m,o2,64));
    float p = (lane<=i) ? __expf(s-m) : 0.f;
    float sum = p;
    for (int o2=32;o2;o2>>=1) sum += __shfl_xor(sum,o2,64);
    float inv = 1.f/sum;
    if (lane < T_) pl[lane] = p*inv;
    float oatt=0.f;
    for (int j=0;j<=i;j++) oatt += pl[j]*Vl[j][lane];
    float num=0.f, den=0.f;
    for (int dd=0; dd<DH_; dd++) {
      float sq = elu1f(qrow[dd]);
      num += sq*memh[dd*DH_+lane];
      den += sq*zh[dd];
    }
    float ov = g*(num/den) + (1.f-g)*oatt;
    o[(tok0 + (size_t)i*HW_)*D_ + (size_t)head*DH_ + lane] = f2b(ov);
  }
}

// ==================================================================================
extern "C" void kernel_launch(void* const* d_in, const int* in_sizes, int n_in,
                              void* d_out, int out_size, void* d_ws, size_t ws_size,
                              hipStream_t stream)
{
  (void)in_sizes; (void)n_in; (void)out_size; (void)ws_size;
  const float* x_in    = (const float*)d_in[0];
  const float* c_in    = (const float*)d_in[1];
  const float* mem_s   = (const float*)d_in[2];
  const float* z_s     = (const float*)d_in[3];
  const float* mem_t   = (const float*)d_in[4];
  const float* z_t     = (const float*)d_in[5];
  const float* w_qkv_s = (const float*)d_in[6];
  const float* w_out_s = (const float*)d_in[7];
  const float* b_out_s = (const float*)d_in[8];
  const float* beta_s  = (const float*)d_in[9];
  const float* w_ada_s = (const float*)d_in[10];
  const float* b_ada_s = (const float*)d_in[11];
  const float* w1_s    = (const float*)d_in[12];
  const float* b1_s    = (const float*)d_in[13];
  const float* w2_s    = (const float*)d_in[14];
  const float* b2_s    = (const float*)d_in[15];
  const float* w_qkv_t = (const float*)d_in[16];
  const float* w_out_t = (const float*)d_in[17];
  const float* b_out_t = (const float*)d_in[18];
  const float* beta_t  = (const float*)d_in[19];
  const float* w_ada_t = (const float*)d_in[20];
  const float* b_ada_t = (const float*)d_in[21];
  const float* w1_t    = (const float*)d_in[22];
  const float* b1_t    = (const float*)d_in[23];
  const float* w2_t    = (const float*)d_in[24];
  const float* b2_t    = (const float*)d_in[25];

  float* out_x  = (float*)d_out;           // 4718592 — also serves as running x
  float* out_ms = out_x + 4718592;
  float* out_zs = out_ms + 2097152;
  float* out_mt = out_zs + 32768;
  float* out_zt = out_mt + 18874368;

  char* wsp = (char*)d_ws;
  auto alloc = [&](size_t bytes)->char* {
    char* p = wsp; wsp += (bytes + 255) & ~(size_t)255; return p;
  };
  u16*   wqkvT = (u16*)  alloc((size_t)3072*1024*2);
  u16*   woutT = (u16*)  alloc((size_t)1024*1024*2);
  u16*   w1T   = (u16*)  alloc((size_t)4096*1024*2);
  u16*   w2T   = (u16*)  alloc((size_t)1024*4096*2);
  float* scbuf = (float*)alloc((size_t)32*1024*4);
  float* ada_s = (float*)alloc((size_t)32*6144*4);
  float* ada_t = (float*)alloc((size_t)32*6144*4);
  u16*   xm    = (u16*)  alloc((size_t)NTOK_*D_*2);
  float* qkv   = (float*)alloc((size_t)NTOK_*3*D_*4);   // aliased: mlp hidden (bf16) fits
  u16*   hbuf  = (u16*)qkv;
  u16*   obuf  = (u16*)  alloc((size_t)NTOK_*D_*2);

  dim3 blk(256);

  // ---- shared prologue
  silu_k<<<128, blk, 0, stream>>>(c_in, scbuf, 32*1024);
  ada_gemm<<<24, blk, 0, stream>>>(scbuf, w_ada_s, b_ada_s, ada_s);
  ada_gemm<<<24, blk, 0, stream>>>(scbuf, w_ada_t, b_ada_t, ada_t);

  // ---- spatial weights -> bf16 transposed
  transpose_w<<<dim3(96,32),  blk, 0, stream>>>(w_qkv_s, wqkvT, 1024, 3072);
  transpose_w<<<dim3(32,32),  blk, 0, stream>>>(w_out_s, woutT, 1024, 1024);
  transpose_w<<<dim3(128,32), blk, 0, stream>>>(w1_s,    w1T,   1024, 4096);
  transpose_w<<<dim3(32,128), blk, 0, stream>>>(w2_s,    w2T,   4096, 1024);

  // ---- spatial branch
  ln_mod<<<NTOK_, blk, 0, stream>>>(x_in, ada_s, 0, 1024, xm);
  gemm_bt<0><<<dim3(24,36), blk, 0, stream>>>(xm, wqkvT, qkv, nullptr, nullptr, nullptr, 0, nullptr,
                                              NTOK_, 3072, 1024);
  memupd_s_k<<<dim3(16,32), blk, 0, stream>>>(qkv, mem_s, z_s, out_ms, out_zs);
  rope_s_k<<<NTOK_, blk, 0, stream>>>(qkv);
  attn_s_k<<<dim3(16,32), blk, 0, stream>>>(qkv, mem_s, z_s, beta_s, obuf);
  gemm_bt<2><<<dim3(8,36), blk, 0, stream>>>(obuf, woutT, out_x, nullptr, b_out_s, ada_s, 2*1024, nullptr,
                                             NTOK_, 1024, 1024);
  ln_mod<<<NTOK_, blk, 0, stream>>>(out_x, ada_s, 3*1024, 4*1024, xm);
  gemm_bt<1><<<dim3(32,36), blk, 0, stream>>>(xm, w1T, nullptr, hbuf, b1_s, nullptr, 0, nullptr,
                                              NTOK_, 4096, 1024);
  gemm_bt<3><<<dim3(8,36), blk, 0, stream>>>(hbuf, w2T, out_x, nullptr, b2_s, ada_s, 5*1024, out_x,
                                             NTOK_, 1024, 4096);

  // ---- temporal weights -> bf16 transposed (reuse buffers)
  transpose_w<<<dim3(96,32),  blk, 0, stream>>>(w_qkv_t, wqkvT, 1024, 3072);
  transpose_w<<<dim3(32,32),  blk, 0, stream>>>(w_out_t, woutT, 1024, 1024);
  transpose_w<<<dim3(128,32), blk, 0, stream>>>(w1_t,    w1T,   1024, 4096);
  transpose_w<<<dim3(32,128), blk, 0, stream>>>(w2_t,    w2T,   4096, 1024);

  // ---- temporal branch
  ln_mod<<<NTOK_, blk, 0, stream>>>(out_x, ada_t, 0, 1024, xm);
  gemm_bt<0><<<dim3(24,36), blk, 0, stream>>>(xm, wqkvT, qkv, nullptr, nullptr, nullptr, 0, nullptr,
                                              NTOK_, 3072, 1024);
  memupd_t_k<<<dim3(16,288), blk, 0, stream>>>(qkv, mem_t, z_t, out_mt, out_zt);
  rope_t_k<<<NTOK_, blk, 0, stream>>>(qkv);
  attn_t_k<<<dim3(16,288), dim3(64), 0, stream>>>(qkv, mem_t, z_t, beta_t, obuf);
  gemm_bt<2><<<dim3(8,36), blk, 0, stream>>>(obuf, woutT, out_x, nullptr, b_out_t, ada_t, 2*1024, nullptr,
                                             NTOK_, 1024, 1024);
  ln_mod<<<NTOK_, blk, 0, stream>>>(out_x, ada_t, 3*1024, 4*1024, xm);
  gemm_bt<1><<<dim3(32,36), blk, 0, stream>>>(xm, w1T, nullptr, hbuf, b1_t, nullptr, 0, nullptr,
                                              NTOK_, 4096, 1024);
  gemm_bt<3><<<dim3(8,36), blk, 0, stream>>>(hbuf, w2T, out_x, nullptr, b2_t, ada_t, 5*1024, out_x,
                                             NTOK_, 1024, 4096);
}

// Round 2
// 1740.952 us; speedup vs baseline: 1.2873x; 1.2873x over previous
//
#include <hip/hip_runtime.h>
#include <stdint.h>

typedef unsigned short u16;
typedef __attribute__((ext_vector_type(8))) short s8v;
typedef __attribute__((ext_vector_type(4))) float f4v;

#define D_     1024
#define HEADS_ 16
#define DH_    64
#define B_     2
#define T_     16
#define H_     9
#define W_     16
#define HW_    144
#define NTOK_  4608
#define MLPH_  4096
#define STRIDE_ 5
#define PI_    3.14159265358979323846f

__device__ __forceinline__ float b2f(u16 u){
  union{float f; unsigned int i;} c; c.i = ((unsigned int)u)<<16; return c.f;
}
__device__ __forceinline__ u16 f2b(float f){
  union{float f; unsigned int i;} c; c.f = f;
  unsigned int r = c.i + 0x7FFFu + ((c.i >> 16) & 1u);
  return (u16)(r >> 16);
}
__device__ __forceinline__ float elu1f(float x){ return x > 0.f ? x + 1.f : expf(x); }

__device__ __forceinline__ uint4 pack8(float4 a, float4 b){
  uint4 r;
  r.x = ((unsigned)f2b(a.y)<<16) | f2b(a.x);
  r.y = ((unsigned)f2b(a.w)<<16) | f2b(a.z);
  r.z = ((unsigned)f2b(b.y)<<16) | f2b(b.x);
  r.w = ((unsigned)f2b(b.w)<<16) | f2b(b.z);
  return r;
}
__device__ __forceinline__ s8v cvt8(float4 a, float4 b){
  s8v r;
  r[0]=(short)f2b(a.x); r[1]=(short)f2b(a.y); r[2]=(short)f2b(a.z); r[3]=(short)f2b(a.w);
  r[4]=(short)f2b(b.x); r[5]=(short)f2b(b.y); r[6]=(short)f2b(b.z); r[7]=(short)f2b(b.w);
  return r;
}
__device__ __forceinline__ s8v cvt8e(float4 a, float4 b){
  s8v r;
  r[0]=(short)f2b(elu1f(a.x)); r[1]=(short)f2b(elu1f(a.y)); r[2]=(short)f2b(elu1f(a.z)); r[3]=(short)f2b(elu1f(a.w));
  r[4]=(short)f2b(elu1f(b.x)); r[5]=(short)f2b(elu1f(b.y)); r[6]=(short)f2b(elu1f(b.z)); r[7]=(short)f2b(elu1f(b.w));
  return r;
}

// async global->LDS, 16 bytes per lane (dest = wave-uniform base + lane*16)
__device__ __forceinline__ void gload16(const u16* g, u16* l){
  __builtin_amdgcn_global_load_lds((const __attribute__((address_space(1))) void*)g,
                                   (__attribute__((address_space(3))) void*)l, 16, 0, 0);
}

// ---------------- weight transpose + f32->bf16: in (K,N) -> out (N,K) ----------------
__global__ __launch_bounds__(256) void transpose_w(const float* __restrict__ in,
                                                   u16* __restrict__ out, int K, int N)
{
  __shared__ float tile[32][33];
  int n0 = blockIdx.x*32, k0 = blockIdx.y*32;
  int tx = threadIdx.x & 31, ty = threadIdx.x >> 5;   // 32 x 8
  #pragma unroll
  for (int i=0;i<4;i++)
    tile[ty+i*8][tx] = in[(size_t)(k0+ty+i*8)*N + n0+tx];
  __syncthreads();
  #pragma unroll
  for (int i=0;i<4;i++)
    out[(size_t)(n0+ty+i*8)*K + k0+tx] = f2b(tile[tx][ty+i*8]);
}

// ---------------- silu ----------------
__global__ void silu_k(const float* __restrict__ c, float* __restrict__ out, int n){
  int i = blockIdx.x*256 + threadIdx.x;
  if (i < n){ float v = c[i]; out[i] = v / (1.f + __expf(-v)); }
}

// ---------------- ada GEMM: out[32][6144] = sc[32][1024] @ w[1024][6144] + b ----------------
__global__ __launch_bounds__(256) void ada_gemm(const float* __restrict__ sc,
                                                const float* __restrict__ w,
                                                const float* __restrict__ b,
                                                float* __restrict__ out)
{
  int j = blockIdx.x*256 + threadIdx.x;
  __shared__ float scl[32*64];
  float acc[32];
  #pragma unroll
  for (int r=0;r<32;r++) acc[r]=0.f;
  for (int k0=0;k0<1024;k0+=64) {
    __syncthreads();
    for (int idx=threadIdx.x; idx<2048; idx+=256) {
      int r = idx>>6, kk = idx&63;
      scl[r*64+kk] = sc[r*1024 + k0 + kk];
    }
    __syncthreads();
    for (int kk=0;kk<64;kk++) {
      float wv = w[(size_t)(k0+kk)*6144 + j];
      #pragma unroll
      for (int r=0;r<32;r++) acc[r] += scl[r*64+kk]*wv;
    }
  }
  float bb = b[j];
  #pragma unroll
  for (int r=0;r<32;r++) out[(size_t)r*6144 + j] = acc[r] + bb;
}

// ---------------- LayerNorm + modulation -> bf16 ----------------
__global__ __launch_bounds__(256) void ln_mod(const float* __restrict__ x,
                                              const float* __restrict__ ada,
                                              int shOff, int scOff,
                                              u16* __restrict__ out)
{
  int n = blockIdx.x, tid = threadIdx.x;
  const float* xr = x + (size_t)n * D_;
  float4 v = *(const float4*)&xr[tid*4];
  float s = v.x+v.y+v.z+v.w;
  __shared__ float red[8];
  for (int o=32;o;o>>=1) s += __shfl_down(s,o,64);
  if ((tid&63)==0) red[tid>>6] = s;
  __syncthreads();
  float mean = (red[0]+red[1]+red[2]+red[3]) * (1.f/D_);
  float d0=v.x-mean, d1=v.y-mean, d2=v.z-mean, d3=v.w-mean;
  float sq = d0*d0+d1*d1+d2*d2+d3*d3;
  for (int o=32;o;o>>=1) sq += __shfl_down(sq,o,64);
  if ((tid&63)==0) red[4+(tid>>6)] = sq;
  __syncthreads();
  float var = (red[4]+red[5]+red[6]+red[7]) * (1.f/D_);
  float rstd = rsqrtf(var + 1e-6f);
  int bt = n / HW_;
  const float* adar = ada + (size_t)bt*6*D_;
  int cidx = tid*4;
  float4 sh = *(const float4*)&adar[shOff + cidx];
  float4 sc = *(const float4*)&adar[scOff + cidx];
  ushort4 o4;
  o4.x = f2b(d0*rstd*(1.f+sc.x)+sh.x);
  o4.y = f2b(d1*rstd*(1.f+sc.y)+sh.y);
  o4.z = f2b(d2*rstd*(1.f+sc.z)+sh.z);
  o4.w = f2b(d3*rstd*(1.f+sc.w)+sh.w);
  *(ushort4*)&out[(size_t)n*D_ + cidx] = o4;
}

// ---------------- MFMA GEMM: C(MxN) = A(MxK bf16) x Bt(NxK bf16)^T ----------------
// MODE 0: store f32
// MODE 1: +bias, gelu(tanh), store bf16
// MODE 2: +bias, *(1+ada[bt][adaOff+c]), store f32
// MODE 3: +bias, *ada[bt][adaOff+c], += xprev, store f32
template<int MODE>
__global__ __launch_bounds__(256) void gemm_bt(
    const u16* __restrict__ A, const u16* __restrict__ Bt,
    float* __restrict__ Cf, u16* __restrict__ Cb,
    const float* __restrict__ bias, const float* __restrict__ ada, int adaOff,
    const float* __restrict__ xprev, int M, int N, int K)
{
  __shared__ u16 As[128*32];
  __shared__ u16 Bs[128*32];
  const int tid = threadIdx.x;
  const int row0 = blockIdx.y*128, col0 = blockIdx.x*128;
  const int lane = tid & 63, wid = tid >> 6;
  const int wr = wid >> 1, wc = wid & 1;
  const int r16 = lane & 15, kg = lane >> 4;

  f4v acc[4][4] = {};
  const u16* Ag = A + (size_t)(row0 + (tid>>2)) * K + (tid&3)*8;
  const u16* Bg = Bt + (size_t)(col0 + (tid>>2)) * K + (tid&3)*8;

  for (int k0 = 0; k0 < K; k0 += 32) {
    __syncthreads();
    gload16(Ag + k0,                As + tid*8);
    gload16(Ag + (size_t)64*K + k0, As + 2048 + tid*8);
    gload16(Bg + k0,                Bs + tid*8);
    gload16(Bg + (size_t)64*K + k0, Bs + 2048 + tid*8);
    __syncthreads();
    s8v af[4], bfv[4];
    #pragma unroll
    for (int mi=0; mi<4; mi++)
      af[mi] = *(const s8v*)&As[(wr*64 + mi*16 + r16)*32 + kg*8];
    #pragma unroll
    for (int ni=0; ni<4; ni++)
      bfv[ni] = *(const s8v*)&Bs[(wc*64 + ni*16 + r16)*32 + kg*8];
    #pragma unroll
    for (int mi=0; mi<4; mi++)
      #pragma unroll
      for (int ni=0; ni<4; ni++)
        acc[mi][ni] = __builtin_amdgcn_mfma_f32_16x16x32_bf16(af[mi], bfv[ni], acc[mi][ni], 0,0,0);
  }
  #pragma unroll
  for (int mi=0; mi<4; mi++)
  #pragma unroll
  for (int ni=0; ni<4; ni++) {
    int rbase = row0 + wr*64 + mi*16 + (lane>>4)*4;
    int c = col0 + wc*64 + ni*16 + (lane&15);
    #pragma unroll
    for (int q=0; q<4; q++) {
      int r = rbase + q;
      float v = acc[mi][ni][q];
      if (MODE == 0) {
        Cf[(size_t)r*N + c] = v;
      } else if (MODE == 1) {
        v += bias[c];
        float t = 0.7978845608028654f * (v + 0.044715f*v*v*v);
        Cb[(size_t)r*N + c] = f2b(0.5f*v*(1.f + tanhf(t)));
      } else if (MODE == 2) {
        v += bias[c];
        float g = ada[(size_t)(r/HW_)*(6*D_) + adaOff + c];
        Cf[(size_t)r*N + c] = v*(1.f+g);
      } else {
        v += bias[c];
        float g = ada[(size_t)(r/HW_)*(6*D_) + adaOff + c];
        Cf[(size_t)r*N + c] = xprev[(size_t)r*N + c] + v*g;
      }
    }
  }
}

// ---------------- spatial memory update (pre-RoPE k,v) ----------------
__global__ __launch_bounds__(256) void memupd_s_k(
  const float* __restrict__ qkv, const float* __restrict__ mem_in, const float* __restrict__ z_in,
  float* __restrict__ mem_out, float* __restrict__ z_out)
{
  int head = blockIdx.x, f = blockIdx.y;
  __shared__ float ek[STRIDE_][DH_];
  __shared__ float ev[STRIDE_][DH_];
  int tid = threadIdx.x;
  const size_t base = (size_t)f*HW_*(3*D_) + (size_t)head*DH_;
  for (int i = tid; i < STRIDE_*DH_; i += 256) {
    int s = i/DH_, d = i%DH_;
    float kv = qkv[base + (size_t)s*(3*D_) + D_ + d];
    ek[s][d] = elu1f(kv) + 1.f;   // elu1(elu1(k)) = elu1(k)+1 since elu1>0
    ev[s][d] = qkv[base + (size_t)s*(3*D_) + 2*D_ + d];
  }
  __syncthreads();
  size_t mbase = ((size_t)f*HEADS_ + head)*DH_*DH_;
  for (int i = tid; i < DH_*DH_; i += 256) {
    int d = i>>6, j = i&63;
    float s = 0.f;
    #pragma unroll
    for (int t=0;t<STRIDE_;t++) s += ek[t][d]*ev[t][j];
    mem_out[mbase+i] = mem_in[mbase+i] + s;
  }
  if (tid < DH_) {
    float s = 0.f;
    for (int t=0;t<HW_;t++)
      s += elu1f(qkv[base + (size_t)t*(3*D_) + D_ + tid]);
    size_t zb = ((size_t)f*HEADS_+head)*DH_ + tid;
    z_out[zb] = z_in[zb] + s;
  }
}

// ---------------- temporal memory update ----------------
__global__ __launch_bounds__(256) void memupd_t_k(
  const float* __restrict__ qkv, const float* __restrict__ mem_in, const float* __restrict__ z_in,
  float* __restrict__ mem_out, float* __restrict__ z_out)
{
  int head = blockIdx.x, g = blockIdx.y;
  int b = g / HW_, hw = g % HW_;
  size_t tok0 = (size_t)b*T_*HW_ + hw;
  __shared__ float ek[STRIDE_][DH_];
  __shared__ float ev[STRIDE_][DH_];
  int tid = threadIdx.x;
  for (int i = tid; i < STRIDE_*DH_; i += 256) {
    int t = i/DH_, d = i%DH_;
    size_t a = (tok0 + (size_t)t*HW_)*(3*D_) + (size_t)head*DH_;
    float kv = qkv[a + D_ + d];
    ek[t][d] = elu1f(kv) + 1.f;
    ev[t][d] = qkv[a + 2*D_ + d];
  }
  __syncthreads();
  size_t mbase = ((size_t)g*HEADS_ + head)*DH_*DH_;
  for (int i = tid; i < DH_*DH_; i += 256) {
    int d = i>>6, j = i&63;
    float s = 0.f;
    #pragma unroll
    for (int t=0;t<STRIDE_;t++) s += ek[t][d]*ev[t][j];
    mem_out[mbase+i] = mem_in[mbase+i] + s;
  }
  if (tid < DH_) {
    float s = 0.f;
    for (int t=0;t<T_;t++)
      s += elu1f(qkv[(tok0 + (size_t)t*HW_)*(3*D_) + D_ + (size_t)head*DH_ + tid]);
    size_t zb = ((size_t)g*HEADS_+head)*DH_ + tid;
    z_out[zb] = z_in[zb] + s;
  }
}

// ---------------- RoPE (in-place on q,k of qkv buffer) ----------------
__global__ __launch_bounds__(256) void rope_s_k(float* __restrict__ qkv)
{
  int n = blockIdx.x;
  int hw = n % HW_;
  int h = hw / W_, w = hw % W_;
  float* qb = qkv + (size_t)n*(3*D_);
  int tid = threadIdx.x;
  #pragma unroll
  for (int rep=0; rep<2; rep++) {
    int p = tid + rep*256;
    int col = p*2;
    int dh = col & 63;
    int i2 = dh >> 1;
    float fv;
    if (i2 < 16) {
      float pos = -1.f + (float)h*(2.f/8.f);
      fv = pos * ((1.f + (float)i2*(127.f/15.f)) * PI_);
    } else {
      float pos = -1.f + (float)w*(2.f/15.f);
      fv = pos * ((1.f + (float)(i2-16)*(127.f/15.f)) * PI_);
    }
    float cs = cosf(fv), sn = sinf(fv);
    float2 q2 = *(float2*)&qb[col];
    float2 k2 = *(float2*)&qb[D_+col];
    float2 qo, ko;
    qo.x = q2.x*cs - q2.y*sn;  qo.y = q2.y*cs + q2.x*sn;
    ko.x = k2.x*cs - k2.y*sn;  ko.y = k2.y*cs + k2.x*sn;
    *(float2*)&qb[col]    = qo;
    *(float2*)&qb[D_+col] = ko;
  }
}

__global__ __launch_bounds__(256) void rope_t_k(float* __restrict__ qkv)
{
  int n = blockIdx.x;
  int t = (n / HW_) % T_;
  float* qb = qkv + (size_t)n*(3*D_);
  int tid = threadIdx.x;
  #pragma unroll
  for (int rep=0; rep<2; rep++) {
    int p = tid + rep*256;
    int col = p*2;
    int dh = col & 63;
    int i2 = dh >> 1;
    float inv = expf(-(float)i2 * (9.210340371976184f/32.f));  // 10000^(-i2/32)
    float fv = (float)t * inv;
    float cs = cosf(fv), sn = sinf(fv);
    float2 q2 = *(float2*)&qb[col];
    float2 k2 = *(float2*)&qb[D_+col];
    float2 qo, ko;
    qo.x = q2.x*cs - q2.y*sn;  qo.y = q2.y*cs + q2.x*sn;
    ko.x = k2.x*cs - k2.y*sn;  ko.y = k2.y*cs + k2.x*sn;
    *(float2*)&qb[col]    = qo;
    *(float2*)&qb[D_+col] = ko;
  }
}

// ---------------- spatial attention via MFMA ----------------
// Per block: one (frame f, head). S=QK^T (9x9 16-tiles), softmax, O=PV,
// R=elu1(Q)@[memT|z] (den folded as col 64). o = g*R/den + (1-g)*O.
// LDS swizzle: 16B-block XOR by (row&7) on byte-offsets < 256 within a row.
__global__ __launch_bounds__(256,2) void attn_s_mfma(
  const float* __restrict__ qkv, const float* __restrict__ mem, const float* __restrict__ z,
  const float* __restrict__ beta, u16* __restrict__ o)
{
  __shared__ u16 Ks[HW_*64];      // [j][d]   row 128B, swizzled
  __shared__ u16 Vt[64*160];      // [d][j]   row 320B, swizzled for j<128
  __shared__ u16 memT[80*72];     // [v][d]   row 144B, swizzled; row64=z, 65..79=0
  __shared__ u16 Pbuf[4*16*160];  // per-wave P chunk, row 320B, swizzled for col<128
  int tid = threadIdx.x, lane = tid & 63, w = tid >> 6;
  int head = blockIdx.x, f = blockIdx.y;
  const int r15 = lane & 15, kg8 = (lane >> 4) * 8, kg4 = (lane >> 4) * 4;
  const int kmask = (r15 & 7) << 4;
  const size_t base = (size_t)f*HW_*(3*D_) + (size_t)head*DH_;

  // ---- stage K (bf16, swizzled)
  for (int vi = tid; vi < HW_*8; vi += 256) {
    int j = vi >> 3, dg = vi & 7;
    const float* src = qkv + base + (size_t)j*(3*D_) + D_ + dg*8;
    float4 a = *(const float4*)src, b = *(const float4*)(src+4);
    *(uint4*)((char*)Ks + j*128 + ((dg*16) ^ ((j&7)<<4))) = pack8(a,b);
  }
  // ---- stage V^T
  for (int j = w; j < HW_; j += 4) {
    float v = qkv[base + (size_t)j*(3*D_) + 2*D_ + lane];
    int cw = j*2;
    int bo = (cw < 256) ? (cw ^ ((lane&7)<<4)) : cw;
    *(u16*)((char*)Vt + lane*320 + bo) = f2b(v);
  }
  for (int e = tid; e < 64*16; e += 256) {            // zero pad j=144..159
    int d = e >> 4, jj = 144 + (e & 15);
    *(u16*)((char*)Vt + d*320 + jj*2) = 0;
  }
  // ---- stage mem^T (+ z row, + zero rows)
  const float* memh = mem + ((size_t)f*HEADS_+head)*DH_*DH_;
  const float* zh   = z   + ((size_t)f*HEADS_+head)*DH_;
  for (int e = tid; e < 4096; e += 256) {
    int d = e >> 6, v = e & 63;
    *(u16*)((char*)memT + v*144 + ((d*2) ^ ((v&7)<<4))) = f2b(memh[e]);
  }
  if (tid < 64) *(u16*)((char*)memT + 64*144 + tid*2) = f2b(zh[tid]);
  for (int e = tid; e < 15*64; e += 256) {
    int r = 65 + (e >> 6), d = e & 63;
    *(u16*)((char*)memT + r*144 + ((d*2) ^ ((r&7)<<4))) = 0;
  }
  // ---- zero P pad cols 144..159 (own wave's chunk)
  char* Pw = (char*)Pbuf + w*5120;
  for (int e = lane; e < 256; e += 64) {
    int r = e >> 4, c = 144 + (e & 15);
    *(u16*)(Pw + r*320 + c*2) = 0;
  }
  __syncthreads();

  float gsig = 1.f/(1.f + __expf(-beta[head]));

  for (int rt = w; rt < 9; rt += 4) {
    // Q row fragment (fp32 in regs, reused for S and retrieve)
    const float* qg = qkv + base + (size_t)(rt*16 + r15)*(3*D_);
    float4 qa = *(const float4*)(qg + kg8);
    float4 qb = *(const float4*)(qg + kg8 + 4);
    float4 qc = *(const float4*)(qg + 32 + kg8);
    float4 qd = *(const float4*)(qg + 32 + kg8 + 4);
    s8v aq0 = cvt8(qa,qb), aq1 = cvt8(qc,qd);

    // ---- S = Q K^T / 8
    f4v sacc[9] = {};
    #pragma unroll
    for (int cb=0; cb<9; cb++) {
      const char* kr = (char*)Ks + (cb*16 + r15)*128;
      s8v b0 = *(const s8v*)(kr + ((kg8*2) ^ kmask));
      s8v b1 = *(const s8v*)(kr + ((kg8*2 + 64) ^ kmask));
      sacc[cb] = __builtin_amdgcn_mfma_f32_16x16x32_bf16(aq0, b0, sacc[cb], 0,0,0);
      sacc[cb] = __builtin_amdgcn_mfma_f32_16x16x32_bf16(aq1, b1, sacc[cb], 0,0,0);
    }
    // ---- softmax over 144 cols (rows live in 16-lane groups)
    float pinv[4];
    #pragma unroll
    for (int q=0; q<4; q++) {
      float m = sacc[0][q];
      #pragma unroll
      for (int cb=1; cb<9; cb++) m = fmaxf(m, sacc[cb][q]);
      m *= 0.125f;
      #pragma unroll
      for (int o2=1; o2<16; o2<<=1) m = fmaxf(m, __shfl_xor(m, o2, 64));
      float ssum = 0.f;
      #pragma unroll
      for (int cb=0; cb<9; cb++) {
        float p = __expf(sacc[cb][q]*0.125f - m);
        sacc[cb][q] = p; ssum += p;
      }
      #pragma unroll
      for (int o2=1; o2<16; o2<<=1) ssum += __shfl_xor(ssum, o2, 64);
      pinv[q] = 1.f/ssum;
    }
    // ---- write P chunk (bf16, swizzled)
    #pragma unroll
    for (int cb=0; cb<9; cb++) {
      int cw = cb*32 + r15*2;
      #pragma unroll
      for (int q=0; q<4; q++) {
        int rw = kg4 + q;
        int bo = (cw < 256) ? (cw ^ ((rw&7)<<4)) : cw;
        *(u16*)(Pw + rw*320 + bo) = f2b(sacc[cb][q]*pinv[q]);
      }
    }
    // ---- O = P V  (same-wave LDS ordering; no barrier needed)
    f4v oacc[4] = {};
    #pragma unroll
    for (int ks=0; ks<5; ks++) {
      int bk = kg8*2 + ks*64;
      int bo = (bk < 256) ? (bk ^ kmask) : bk;
      s8v ap = *(const s8v*)(Pw + r15*320 + bo);
      #pragma unroll
      for (int nt=0; nt<4; nt++) {
        s8v bv = *(const s8v*)((char*)Vt + (nt*16 + r15)*320 + bo);
        oacc[nt] = __builtin_amdgcn_mfma_f32_16x16x32_bf16(ap, bv, oacc[nt], 0,0,0);
      }
    }
    // ---- retrieve: [num | den] = elu1(Q) @ [memT | z]
    s8v ae0 = cvt8e(qa,qb), ae1 = cvt8e(qc,qd);
    f4v racc[5] = {};
    #pragma unroll
    for (int ks=0; ks<2; ks++) {
      int bo = (kg8*2 + ks*64) ^ kmask;
      s8v aq = ks ? ae1 : ae0;
      #pragma unroll
      for (int nt=0; nt<5; nt++) {
        s8v bm = *(const s8v*)((char*)memT + (nt*16 + r15)*144 + bo);
        racc[nt] = __builtin_amdgcn_mfma_f32_16x16x32_bf16(aq, bm, racc[nt], 0,0,0);
      }
    }
    // ---- combine + store
    #pragma unroll
    for (int q=0; q<4; q++) {
      float den = __shfl(racc[4][q], lane & 48, 64);
      int r = rt*16 + kg4 + q;
      size_t ob = ((size_t)(f*HW_ + r))*D_ + (size_t)head*DH_;
      #pragma unroll
      for (int nt=0; nt<4; nt++) {
        float ov = gsig*(racc[nt][q]/den) + (1.f-gsig)*oacc[nt][q];
        o[ob + nt*16 + r15] = f2b(ov);
      }
    }
  }
}

// ---------------- temporal attention: causal sdpa(16) + retrieve, 4 waves ----------------
__global__ __launch_bounds__(256) void attn_t_k(
  const float* __restrict__ qkv, const float* __restrict__ mem, const float* __restrict__ z,
  const float* __restrict__ beta, u16* __restrict__ o)
{
  int head = blockIdx.x, gi = blockIdx.y;
  int b = gi / HW_, hw = gi % HW_;
  size_t tok0 = (size_t)b*T_*HW_ + hw;
  __shared__ float Kl[T_*65];     // [t][d] +1 pad
  __shared__ float Vl[T_*65];
  __shared__ float mL[64*65];     // [d][v] +1 pad
  __shared__ float zl[64];
  __shared__ float ql[4][64];
  __shared__ float eql[4][64];
  __shared__ float pl[4][16];
  int tid = threadIdx.x, lane = tid & 63, w = tid >> 6;

  for (int e = tid; e < T_*64; e += 256) {
    int t = e >> 6, d = e & 63;
    size_t a = (tok0 + (size_t)t*HW_)*(3*D_) + (size_t)head*DH_;
    Kl[t*65+d] = qkv[a + D_ + d];
    Vl[t*65+d] = qkv[a + 2*D_ + d];
  }
  const float* memh = mem + ((size_t)gi*HEADS_+head)*DH_*DH_;
  for (int e = tid; e < 4096; e += 256)
    mL[(e>>6)*65 + (e&63)] = memh[e];
  if (tid < 64) zl[tid] = z[((size_t)gi*HEADS_+head)*DH_ + tid];
  __syncthreads();

  float gsig = 1.f/(1.f + __expf(-beta[head]));
  int j = lane & 15, gq = lane >> 4;

  for (int ii = 0; ii < 4; ii++) {
    int i = w + ii*4;   // rows interleaved across waves for balance
    const float* qrow = qkv + (tok0 + (size_t)i*HW_)*(3*D_) + (size_t)head*DH_;
    float qv = qrow[lane];
    ql[w][lane] = qv;
    float e1 = elu1f(qv);
    eql[w][lane] = e1;
    float den = e1 * zl[lane];
    #pragma unroll
    for (int o2=32; o2; o2>>=1) den += __shfl_xor(den, o2, 64);
    // QK (lane j = col, 4 d-groups reduced via shuffles)
    float s = 0.f;
    #pragma unroll
    for (int cc=0; cc<16; cc++) s += ql[w][gq*16+cc] * Kl[j*65 + gq*16 + cc];
    s += __shfl_xor(s, 16, 64); s += __shfl_xor(s, 32, 64);
    s *= 0.125f;
    bool valid = (j <= i);
    float sv = valid ? s : -3.4e38f;
    float m = sv;
    #pragma unroll
    for (int o2=1; o2<16; o2<<=1) m = fmaxf(m, __shfl_xor(m, o2, 64));
    float p = valid ? __expf(s - m) : 0.f;
    float ps = p;
    #pragma unroll
    for (int o2=1; o2<16; o2<<=1) ps += __shfl_xor(ps, o2, 64);
    if (lane < 16) pl[w][lane] = p/ps;
    // PV + retrieve (lane = output channel)
    float oatt = 0.f;
    for (int jj=0; jj<=i; jj++) oatt += pl[w][jj]*Vl[jj*65 + lane];
    float num = 0.f;
    #pragma unroll 8
    for (int d=0; d<64; d++) num += eql[w][d]*mL[d*65 + lane];
    float ov = gsig*(num/den) + (1.f-gsig)*oatt;
    o[(tok0 + (size_t)i*HW_)*D_ + (size_t)head*DH_ + lane] = f2b(ov);
  }
}

// ==================================================================================
extern "C" void kernel_launch(void* const* d_in, const int* in_sizes, int n_in,
                              void* d_out, int out_size, void* d_ws, size_t ws_size,
                              hipStream_t stream)
{
  (void)in_sizes; (void)n_in; (void)out_size; (void)ws_size;
  const float* x_in    = (const float*)d_in[0];
  const float* c_in    = (const float*)d_in[1];
  const float* mem_s   = (const float*)d_in[2];
  const float* z_s     = (const float*)d_in[3];
  const float* mem_t   = (const float*)d_in[4];
  const float* z_t     = (const float*)d_in[5];
  const float* w_qkv_s = (const float*)d_in[6];
  const float* w_out_s = (const float*)d_in[7];
  const float* b_out_s = (const float*)d_in[8];
  const float* beta_s  = (const float*)d_in[9];
  const float* w_ada_s = (const float*)d_in[10];
  const float* b_ada_s = (const float*)d_in[11];
  const float* w1_s    = (const float*)d_in[12];
  const float* b1_s    = (const float*)d_in[13];
  const float* w2_s    = (const float*)d_in[14];
  const float* b2_s    = (const float*)d_in[15];
  const float* w_qkv_t = (const float*)d_in[16];
  const float* w_out_t = (const float*)d_in[17];
  const float* b_out_t = (const float*)d_in[18];
  const float* beta_t  = (const float*)d_in[19];
  const float* w_ada_t = (const float*)d_in[20];
  const float* b_ada_t = (const float*)d_in[21];
  const float* w1_t    = (const float*)d_in[22];
  const float* b1_t    = (const float*)d_in[23];
  const float* w2_t    = (const float*)d_in[24];
  const float* b2_t    = (const float*)d_in[25];

  float* out_x  = (float*)d_out;           // 4718592 — also serves as running x
  float* out_ms = out_x + 4718592;
  float* out_zs = out_ms + 2097152;
  float* out_mt = out_zs + 32768;
  float* out_zt = out_mt + 18874368;

  char* wsp = (char*)d_ws;
  auto alloc = [&](size_t bytes)->char* {
    char* p = wsp; wsp += (bytes + 255) & ~(size_t)255; return p;
  };
  u16*   wqkvT = (u16*)  alloc((size_t)3072*1024*2);
  u16*   woutT = (u16*)  alloc((size_t)1024*1024*2);
  u16*   w1T   = (u16*)  alloc((size_t)4096*1024*2);
  u16*   w2T   = (u16*)  alloc((size_t)1024*4096*2);
  float* scbuf = (float*)alloc((size_t)32*1024*4);
  float* ada_s = (float*)alloc((size_t)32*6144*4);
  float* ada_t = (float*)alloc((size_t)32*6144*4);
  u16*   xm    = (u16*)  alloc((size_t)NTOK_*D_*2);
  float* qkv   = (float*)alloc((size_t)NTOK_*3*D_*4);   // aliased: mlp hidden (bf16) fits
  u16*   hbuf  = (u16*)qkv;
  u16*   obuf  = (u16*)  alloc((size_t)NTOK_*D_*2);

  dim3 blk(256);

  // ---- shared prologue
  silu_k<<<128, blk, 0, stream>>>(c_in, scbuf, 32*1024);
  ada_gemm<<<24, blk, 0, stream>>>(scbuf, w_ada_s, b_ada_s, ada_s);
  ada_gemm<<<24, blk, 0, stream>>>(scbuf, w_ada_t, b_ada_t, ada_t);

  // ---- spatial weights -> bf16 transposed
  transpose_w<<<dim3(96,32),  blk, 0, stream>>>(w_qkv_s, wqkvT, 1024, 3072);
  transpose_w<<<dim3(32,32),  blk, 0, stream>>>(w_out_s, woutT, 1024, 1024);
  transpose_w<<<dim3(128,32), blk, 0, stream>>>(w1_s,    w1T,   1024, 4096);
  transpose_w<<<dim3(32,128), blk, 0, stream>>>(w2_s,    w2T,   4096, 1024);

  // ---- spatial branch
  ln_mod<<<NTOK_, blk, 0, stream>>>(x_in, ada_s, 0, 1024, xm);
  gemm_bt<0><<<dim3(24,36), blk, 0, stream>>>(xm, wqkvT, qkv, nullptr, nullptr, nullptr, 0, nullptr,
                                              NTOK_, 3072, 1024);
  memupd_s_k<<<dim3(16,32), blk, 0, stream>>>(qkv, mem_s, z_s, out_ms, out_zs);
  rope_s_k<<<NTOK_, blk, 0, stream>>>(qkv);
  attn_s_mfma<<<dim3(16,32), blk, 0, stream>>>(qkv, mem_s, z_s, beta_s, obuf);
  gemm_bt<2><<<dim3(8,36), blk, 0, stream>>>(obuf, woutT, out_x, nullptr, b_out_s, ada_s, 2*1024, nullptr,
                                             NTOK_, 1024, 1024);
  ln_mod<<<NTOK_, blk, 0, stream>>>(out_x, ada_s, 3*1024, 4*1024, xm);
  gemm_bt<1><<<dim3(32,36), blk, 0, stream>>>(xm, w1T, nullptr, hbuf, b1_s, nullptr, 0, nullptr,
                                              NTOK_, 4096, 1024);
  gemm_bt<3><<<dim3(8,36), blk, 0, stream>>>(hbuf, w2T, out_x, nullptr, b2_s, ada_s, 5*1024, out_x,
                                             NTOK_, 1024, 4096);

  // ---- temporal weights -> bf16 transposed (reuse buffers)
  transpose_w<<<dim3(96,32),  blk, 0, stream>>>(w_qkv_t, wqkvT, 1024, 3072);
  transpose_w<<<dim3(32,32),  blk, 0, stream>>>(w_out_t, woutT, 1024, 1024);
  transpose_w<<<dim3(128,32), blk, 0, stream>>>(w1_t,    w1T,   1024, 4096);
  transpose_w<<<dim3(32,128), blk, 0, stream>>>(w2_t,    w2T,   4096, 1024);

  // ---- temporal branch
  ln_mod<<<NTOK_, blk, 0, stream>>>(out_x, ada_t, 0, 1024, xm);
  gemm_bt<0><<<dim3(24,36), blk, 0, stream>>>(xm, wqkvT, qkv, nullptr, nullptr, nullptr, 0, nullptr,
                                              NTOK_, 3072, 1024);
  memupd_t_k<<<dim3(16,288), blk, 0, stream>>>(qkv, mem_t, z_t, out_mt, out_zt);
  rope_t_k<<<NTOK_, blk, 0, stream>>>(qkv);
  attn_t_k<<<dim3(16,288), blk, 0, stream>>>(qkv, mem_t, z_t, beta_t, obuf);
  gemm_bt<2><<<dim3(8,36), blk, 0, stream>>>(obuf, woutT, out_x, nullptr, b_out_t, ada_t, 2*1024, nullptr,
                                             NTOK_, 1024, 1024);
  ln_mod<<<NTOK_, blk, 0, stream>>>(out_x, ada_t, 3*1024, 4*1024, xm);
  gemm_bt<1><<<dim3(32,36), blk, 0, stream>>>(xm, w1T, nullptr, hbuf, b1_t, nullptr, 0, nullptr,
                                              NTOK_, 4096, 1024);
  gemm_bt<3><<<dim3(8,36), blk, 0, stream>>>(hbuf, w2T, out_x, nullptr, b2_t, ada_t, 5*1024, out_x,
                                             NTOK_, 1024, 4096);
}